// Round 1
// baseline (330.759 us; speedup 1.0000x reference)
//
#include <hip/hip_runtime.h>
#include <hip/hip_bf16.h>
#include <math.h>

// Problem constants: x[B=16][T=4096][D=512], W[512][512], v[512]
#define BB 16
#define TT 4096
#define DD 512
#define MM (BB*TT)   // 65536 rows

typedef __bf16 bf16x8 __attribute__((ext_vector_type(8)));
typedef float  f32x4  __attribute__((ext_vector_type(4)));

__device__ inline unsigned short f2bf(float f) {
    unsigned u = __builtin_bit_cast(unsigned, f) + 0x8000u;  // round-half-away
    return (unsigned short)(u >> 16);
}

// pack two fp32 -> two bf16 in one u32 (2 v_add + 1 v_perm)
__device__ inline unsigned pack_bf16x2(float lo, float hi) {
    unsigned u0 = __builtin_bit_cast(unsigned, lo) + 0x8000u;
    unsigned u1 = __builtin_bit_cast(unsigned, hi) + 0x8000u;
    return __builtin_amdgcn_perm(u1, u0, 0x07060302);  // [u1.hi16, u0.hi16]
}

// fast tanh: 1 - 2/(e^{2y}+1).  |y| <~ 2 here, no overflow concerns.
__device__ inline float tanh_fast(float y) {
    float e = __expf(2.0f * y);
    return 1.0f - 2.0f * __builtin_amdgcn_rcpf(e + 1.0f);
}

// ---------------- W fp32 -> Wb bf16, wave-stream fragment order ----------------
// NEW layout for 64row x 128col (col-quarter) waves:
//   fid = ((qh*4 + p)*16 + s)*2 + ni     (qh = wave's col-quarter, p = 32-col pass)
// lane of frag holds B[k = s*32 + (lane>>4)*8 + j][n = qh*128 + p*32 + ni*16 + (lane&15)]
// => per col-quarter the K-loop B reads are ONE monotone 2 KB/step 128 KB stream.
__global__ void wb_kernel(const float* __restrict__ W, unsigned short* __restrict__ Wb) {
    int u = blockIdx.x * 256 + threadIdx.x;   // 0..32767
    int lane = u & 63;
    int fid  = u >> 6;                        // 0..511
    int ni = fid & 1;
    int s  = (fid >> 1) & 15;
    int p  = (fid >> 5) & 3;
    int qh = fid >> 7;
    int n  = qh * 128 + p * 32 + ni * 16 + (lane & 15);
    int k0 = s * 32 + (lane >> 4) * 8;
    unsigned short o[8];
    #pragma unroll
    for (int j = 0; j < 8; j++) o[j] = f2bf(W[(size_t)(k0 + j) * DD + n]);
    *(uint4*)(Wb + (size_t)u * 8) = *(uint4*)o;   // coalesced 16 B store
}

// ---------------- Fused GEMM + tanh + v-dot + online-softmax partial pool ----------------
// Block = 64 rows x full N=512 x full K=512.  4 waves, each wave = ALL 64 rows x a
// 128-col quarter (qh = wid): 4 passes of a 64x32 acc tile (4x2 16x16x32 frags,
// full-K accumulate).  vs prior 32x256 waves: B L2 traffic halves (512 MB total),
// and each K-step runs 8 MFMAs per 2 B-loads (was 4) -> 2x latency tolerance.
// B streamed via ONE rolling pointer, ring-8 (7-step lookahead ~= 269 cyc of
// wave-time vs ~200-300 cyc L2 latency).  A from LDS via ring-4 (3-step lookahead
// ~= 115 cyc vs ~120 cyc LDS latency).  Ring sizes divide 16 so all indices stay
// compile-time across the rolled pass loop (no scratch).  ZERO barriers in K-loop.
// A-strip (64x512 bf16 = 64 KB) staged ONCE in LDS (fp32->bf16, XOR chunk swizzle).
// Epilogue: block-local softmax (m,Z) + weighted x-sum from LDS -> num[512] partial.
// x is read from HBM exactly ONCE in the whole pipeline.
// VGPR budget: b 64 + a 64 + acc 32 + vpart 16 + vv 8 + addr ~25  => ~210 < 256.
__global__ __launch_bounds__(256, 2) void scorepool_kernel(
        const float* __restrict__ x, const unsigned short* __restrict__ Wb,
        const float* __restrict__ v,
        float* __restrict__ num_ws, float* __restrict__ mz_ws) {
    __shared__ unsigned short As[64 * DD];   // 64 KB
    __shared__ float sbuf[4][64];
    __shared__ float ew[64];
    __shared__ float mzsh[2];
    __shared__ float psum[4][DD];            // 8 KB

    const int tid  = threadIdx.x;
    const int m0   = blockIdx.x * 64;
    const int qh   = tid >> 6;         // wave col-quarter
    const int lane = tid & 63;
    const int l15  = lane & 15;
    const int q    = lane >> 4;
    const int r3   = l15 & 7;

    // ---- Stage A: 64 rows x 512 cols fp32 -> bf16, XOR-swizzled.
    #pragma unroll 4
    for (int i = 0; i < 16; i++) {
        int u = i * 256 + tid;           // 0..4095 (16-B output chunk id)
        int r = u >> 6;                  // 64 chunks per row
        int c = u & 63;
        const float* gp = x + (size_t)(m0 + r) * DD + c * 8;
        float4 f0 = *(const float4*)(gp);
        float4 f1 = *(const float4*)(gp + 4);
        uint4 o;
        o.x = pack_bf16x2(f0.x, f0.y);
        o.y = pack_bf16x2(f0.z, f0.w);
        o.z = pack_bf16x2(f1.x, f1.y);
        o.w = pack_bf16x2(f1.z, f1.w);
        *(uint4*)(&As[r * DD + (c ^ (r & 7)) * 8]) = o;
    }

    // ---- Prime B ring-8 (7-step lookahead; L2 latency hides under the barrier
    //      drain of the staging loads).  Stream padded: tail overrun (<=16 KB,
    //      computed 16382 B worst case) stays inside the ws pad.
    const unsigned short* bqp = Wb + (size_t)qh * 65536 + lane * 8;
    bf16x8 b[8][2];
    #pragma unroll
    for (int g = 0; g < 7; g++) {
        b[g][0] = *(const bf16x8*)(bqp);
        b[g][1] = *(const bf16x8*)(bqp + 512);
        bqp += 1024;
    }

    // per-pass v values, hoisted out of the loop (8 VGPRs)
    float vv[4][2];
    #pragma unroll
    for (int pp = 0; pp < 4; pp++) {
        vv[pp][0] = v[qh * 128 + pp * 32 + l15];
        vv[pp][1] = v[qh * 128 + pp * 32 + 16 + l15];
    }

    __syncthreads();   // the only barrier before the epilogue

    float vpart[4][4];
    #pragma unroll
    for (int mi = 0; mi < 4; mi++)
        #pragma unroll
        for (int rr = 0; rr < 4; rr++)
            vpart[mi][rr] = 0.f;

    // A-frag: row R = mi*16 + l15, logical chunk c = s*4+q, stored at c^(R&7)
    // (mi*16 == 0 mod 8, so R&7 == l15&7 == r3)
#define A_FRAG(mi, s) (*(const bf16x8*)(&As[((mi) * 16 + l15) * DD + ((((s) * 4 + q) ^ r3) * 8)]))

    bf16x8 a[4][4];                    // ring-4 over s, 3-step lookahead
    #pragma unroll
    for (int mi = 0; mi < 4; mi++) {
        a[0][mi] = A_FRAG(mi, 0);
        a[1][mi] = A_FRAG(mi, 1);
        a[2][mi] = A_FRAG(mi, 2);
    }

    #pragma unroll 1
    for (int p = 0; p < 4; p++) {
        f32x4 acc[4][2];
        #pragma unroll
        for (int mi = 0; mi < 4; mi++) {
            acc[mi][0] = (f32x4){0.f, 0.f, 0.f, 0.f};
            acc[mi][1] = (f32x4){0.f, 0.f, 0.f, 0.f};
        }

        #pragma unroll
        for (int s = 0; s < 16; s++) {
            const int ns = (s + 3) & 15;     // pass p+1 reuses same A data (wraps)
            #pragma unroll
            for (int mi = 0; mi < 4; mi++) a[(s + 3) & 3][mi] = A_FRAG(mi, ns);
            // B stream, 7-step lookahead (16 % 8 == 0: seamless across passes)
            b[(s + 7) & 7][0] = *(const bf16x8*)(bqp);
            b[(s + 7) & 7][1] = *(const bf16x8*)(bqp + 512);
            bqp += 1024;
            #pragma unroll
            for (int mi = 0; mi < 4; mi++)
                #pragma unroll
                for (int ni = 0; ni < 2; ni++)
                    acc[mi][ni] = __builtin_amdgcn_mfma_f32_16x16x32_bf16(
                        a[s & 3][mi], b[s & 7][ni], acc[mi][ni], 0, 0, 0);
        }

        // per-pass epilogue: tanh + v-dot into per-row partials
        // C/D layout (16x16): col = lane&15, row = q*4 + rr  [m89/m91 verified]
        #pragma unroll
        for (int mi = 0; mi < 4; mi++)
            #pragma unroll
            for (int rr = 0; rr < 4; rr++)
                vpart[mi][rr] += tanh_fast(acc[mi][0][rr]) * vv[p][0]
                               + tanh_fast(acc[mi][1][rr]) * vv[p][1];
    }
#undef A_FRAG

    // cross-lane reduce over the 16 col-lanes -> per-quarter row partials
    #pragma unroll
    for (int mi = 0; mi < 4; mi++)
        #pragma unroll
        for (int rr = 0; rr < 4; rr++) {
            float sum = vpart[mi][rr];
            sum += __shfl_xor(sum, 1);
            sum += __shfl_xor(sum, 2);
            sum += __shfl_xor(sum, 4);
            sum += __shfl_xor(sum, 8);
            if (l15 == 0)
                sbuf[qh][mi * 16 + q * 4 + rr] = sum;
        }
    __syncthreads();

    // wave 0: row scores (sum of 4 quarter-partials) -> block max m, e_r, Z
    if (tid < 64) {
        float sc = sbuf[0][tid] + sbuf[1][tid] + sbuf[2][tid] + sbuf[3][tid];
        float m = sc;
        #pragma unroll
        for (int off = 32; off; off >>= 1) m = fmaxf(m, __shfl_xor(m, off));
        float e = __expf(sc - m);
        float z = e;
        #pragma unroll
        for (int off = 32; off; off >>= 1) z += __shfl_xor(z, off);
        ew[tid] = e;
        if (tid == 0) { mzsh[0] = m; mzsh[1] = z; }
    }
    __syncthreads();

    // weighted x-sum from LDS: thread = (rg = tid>>6 row group, cx = tid&63 chunk)
    // num[d] partial = sum_r e_r * xb[r][d]
    const int cx = tid & 63;
    const int rg = tid >> 6;
    float nacc[8];
    #pragma unroll
    for (int j = 0; j < 8; j++) nacc[j] = 0.f;
    #pragma unroll 4
    for (int i = 0; i < 16; i++) {
        int r = rg * 16 + i;
        uint4 u = *(const uint4*)(&As[r * DD + ((cx ^ (r & 7)) * 8)]);
        float e = ew[r];
        nacc[0] += e * __builtin_bit_cast(float, u.x << 16);
        nacc[1] += e * __builtin_bit_cast(float, u.x & 0xFFFF0000u);
        nacc[2] += e * __builtin_bit_cast(float, u.y << 16);
        nacc[3] += e * __builtin_bit_cast(float, u.y & 0xFFFF0000u);
        nacc[4] += e * __builtin_bit_cast(float, u.z << 16);
        nacc[5] += e * __builtin_bit_cast(float, u.z & 0xFFFF0000u);
        nacc[6] += e * __builtin_bit_cast(float, u.w << 16);
        nacc[7] += e * __builtin_bit_cast(float, u.w & 0xFFFF0000u);
    }
    *(float4*)(&psum[rg][cx * 8])     = *(float4*)(&nacc[0]);
    *(float4*)(&psum[rg][cx * 8 + 4]) = *(float4*)(&nacc[4]);
    __syncthreads();

    if (tid < 128) {
        int c = tid * 4;
        f32x4 f = *(const f32x4*)(&psum[0][c]);
        f += *(const f32x4*)(&psum[1][c]);
        f += *(const f32x4*)(&psum[2][c]);
        f += *(const f32x4*)(&psum[3][c]);
        *(f32x4*)(num_ws + (size_t)blockIdx.x * DD + c) = f;
    }
    if (tid == 0) {
        mz_ws[2 * blockIdx.x]     = mzsh[0];
        mz_ws[2 * blockIdx.x + 1] = mzsh[1];
    }
}

// ---------------- Combine: merge 64 chunk-partials per batch -> out[b][512] ----------------
__global__ void combine_kernel(const float* __restrict__ num_ws,
                               const float* __restrict__ mz_ws,
                               float* __restrict__ out) {
    __shared__ float fs[64];
    __shared__ float sinv_sh;
    const int b   = blockIdx.x;
    const int tid = threadIdx.x;

    if (tid < 64) {
        float m = mz_ws[(b * 64 + tid) * 2];
        float z = mz_ws[(b * 64 + tid) * 2 + 1];
        float M = m;
        #pragma unroll
        for (int off = 32; off; off >>= 1) M = fmaxf(M, __shfl_xor(M, off));
        float f  = __expf(m - M);
        float fz = f * z;
        #pragma unroll
        for (int off = 32; off; off >>= 1) fz += __shfl_xor(fz, off);
        fs[tid] = f;
        if (tid == 0) sinv_sh = 1.0f / fz;
    }
    __syncthreads();

    float a0 = 0.f, a1 = 0.f;
    #pragma unroll 4
    for (int c = 0; c < 64; c++) {
        float f = fs[c];
        const float* np = num_ws + (size_t)(b * 64 + c) * DD;
        a0 += f * np[tid];
        a1 += f * np[tid + 256];
    }
    const float sinv = sinv_sh;
    out[b * DD + tid]       = a0 * sinv;
    out[b * DD + tid + 256] = a1 * sinv;
}

extern "C" void kernel_launch(void* const* d_in, const int* in_sizes, int n_in,
                              void* d_out, int out_size, void* d_ws, size_t ws_size,
                              hipStream_t stream) {
    (void)in_sizes; (void)n_in; (void)out_size; (void)ws_size;
    const float* x = (const float*)d_in[0];
    const float* W = (const float*)d_in[1];
    const float* v = (const float*)d_in[2];
    float* out = (float*)d_out;

    // ws: Wb 512 KB + 16 KB stream-overrun pad | num 1024x512 fp32 (2 MB) | mz 1024x2 fp32
    unsigned short* Wb = (unsigned short*)d_ws;
    float* num_ws      = (float*)((char*)d_ws + 512 * 1024 + 16 * 1024);
    float* mz_ws       = (float*)((char*)d_ws + 512 * 1024 + 16 * 1024 + 2 * 1024 * 1024);

    wb_kernel<<<128, 256, 0, stream>>>(W, Wb);

    scorepool_kernel<<<MM / 64, 256, 0, stream>>>(x, Wb, v, num_ws, mz_ws);

    combine_kernel<<<BB, 256, 0, stream>>>(num_ws, mz_ws, out);
}

// Round 3
// 243.931 us; speedup vs baseline: 1.3559x; 1.3559x over previous
//
#include <hip/hip_runtime.h>
#include <hip/hip_bf16.h>
#include <math.h>

// Problem constants: x[B=16][T=4096][D=512], W[512][512], v[512]
#define BB 16
#define TT 4096
#define DD 512
#define MM (BB*TT)   // 65536 rows

typedef __bf16 bf16x8 __attribute__((ext_vector_type(8)));
typedef float  f32x4  __attribute__((ext_vector_type(4)));

__device__ inline unsigned short f2bf(float f) {
    unsigned u = __builtin_bit_cast(unsigned, f) + 0x8000u;  // round-half-away
    return (unsigned short)(u >> 16);
}

// pack two fp32 -> two bf16 in one u32 (2 v_add + 1 v_perm)
__device__ inline unsigned pack_bf16x2(float lo, float hi) {
    unsigned u0 = __builtin_bit_cast(unsigned, lo) + 0x8000u;
    unsigned u1 = __builtin_bit_cast(unsigned, hi) + 0x8000u;
    return __builtin_amdgcn_perm(u1, u0, 0x07060302);  // [u1.hi16, u0.hi16]
}

// fast tanh: 1 - 2/(e^{2y}+1).  |y| <~ 2 here, no overflow concerns.
__device__ inline float tanh_fast(float y) {
    float e = __expf(2.0f * y);
    return 1.0f - 2.0f * __builtin_amdgcn_rcpf(e + 1.0f);
}

// ---------------- W fp32 -> Wb bf16, wave-stream fragment order ----------------
// frag id fid = ((h*8 + p)*16 + s)*2 + ni   (h = col-half of the wave pair)
// lane of frag holds B[k = s*32 + (lane>>4)*8 + j][n = h*256 + p*32 + ni*16 + (lane&15)]
// => per col-half the K-loop B reads are ONE monotone 2 KB/step stream.
__global__ void wb_kernel(const float* __restrict__ W, unsigned short* __restrict__ Wb) {
    int u = blockIdx.x * 256 + threadIdx.x;   // 0..32767
    int lane = u & 63;
    int fid  = u >> 6;                        // 0..511
    int ni = fid & 1;
    int s  = (fid >> 1) & 15;
    int p  = (fid >> 5) & 7;
    int h  = fid >> 8;
    int n  = h * 256 + p * 32 + ni * 16 + (lane & 15);
    int k0 = s * 32 + (lane >> 4) * 8;
    unsigned short o[8];
    #pragma unroll
    for (int j = 0; j < 8; j++) o[j] = f2bf(W[(size_t)(k0 + j) * DD + n]);
    *(uint4*)(Wb + (size_t)u * 8) = *(uint4*)o;   // coalesced 16 B store
}

// ---------------- Fused GEMM + tanh + v-dot + online-softmax partial pool ----------------
// Block = 64 rows (one batch's chunk) x full N=512 x full K=512.  4 waves:
// wave w: rows (w&1)*32..+32, col-half h=w>>1; 8 passes of a 32x32 acc tile
// (2x2 16x16x32 MFMA frags, full-K accumulate).  A-strip (64x512 bf16 = 64 KB)
// staged ONCE in LDS (fp32->bf16, XOR chunk swizzle) via NON-TEMPORAL loads so
// the 128 MB x stream does not evict W's 512 KB copy from each XCD L2 (R1 theory:
// B-stream was riding ~500cyc L3 latency; nt keeps it ~200cyc L2-hit).
// B streamed via ONE rolling pointer, ring-4 (3-step lookahead; stream padded so
// no guards).  A from LDS via ring-4 (3-step ~= 115cyc lookahead vs ~120cyc LDS
// latency; R0 had ring-2 = 19cyc).  ZERO barriers in the K-loop.
// Epilogue: block-local softmax (m,Z) + weighted x-sum from LDS -> num[512] partial.
// x is read from HBM exactly ONCE in the whole pipeline.
// VGPR budget (R1 spill lesson: stay well under 128): a 32 + b 32 + acc 16 +
// vpart 8 + addr ~25  => ~115.  If VGPR>=128 AND WRITE_SIZE >> 2MB: A-ring spilled.
__global__ __launch_bounds__(256, 2) void scorepool_kernel(
        const float* __restrict__ x, const unsigned short* __restrict__ Wb,
        const float* __restrict__ v,
        float* __restrict__ num_ws, float* __restrict__ mz_ws) {
    __shared__ unsigned short As[64 * DD];   // 64 KB
    __shared__ float sbuf[2][64];
    __shared__ float ew[64];
    __shared__ float mzsh[2];
    __shared__ float psum[4][DD];            // 8 KB

    const int tid  = threadIdx.x;
    const int m0   = blockIdx.x * 64;
    const int wid  = tid >> 6;
    const int lane = tid & 63;
    const int l15  = lane & 15;
    const int q    = lane >> 4;
    const int r3   = l15 & 7;
    const int wr   = (wid & 1) * 32;   // wave row base
    const int wh   = wid >> 1;         // wave col half

    // ---- Stage A: 64 rows x 512 cols fp32 -> bf16, XOR-swizzled.  NT loads:
    //      x is single-use here; keep it out of L2's LRU so W stays resident.
    //      (nontemporal builtin needs ext-vector types, not HIP_vector_type.)
    #pragma unroll 4
    for (int i = 0; i < 16; i++) {
        int u = i * 256 + tid;           // 0..4095 (16-B output chunk id)
        int r = u >> 6;                  // 64 chunks per row
        int c = u & 63;
        const float* gp = x + (size_t)(m0 + r) * DD + c * 8;
        f32x4 f0 = __builtin_nontemporal_load((const f32x4*)(gp));
        f32x4 f1 = __builtin_nontemporal_load((const f32x4*)(gp + 4));
        uint4 o;
        o.x = pack_bf16x2(f0.x, f0.y);
        o.y = pack_bf16x2(f0.z, f0.w);
        o.z = pack_bf16x2(f1.x, f1.y);
        o.w = pack_bf16x2(f1.z, f1.w);
        *(uint4*)(&As[r * DD + (c ^ (r & 7)) * 8]) = o;
    }

    // ---- Prime B ring (after staging so boundary pressure stays low;
    //      L2 latency hides under the barrier drain of the staging loads).
    const unsigned short* bqp = Wb + (size_t)wh * 131072 + lane * 8;
    bf16x8 b[4][2];
    #pragma unroll
    for (int g = 0; g < 3; g++) {
        b[g][0] = *(const bf16x8*)(bqp);
        b[g][1] = *(const bf16x8*)(bqp + 512);
        bqp += 1024;
    }

    __syncthreads();   // the only barrier before the epilogue

    float vpart[2][4];
    #pragma unroll
    for (int mi = 0; mi < 2; mi++)
        #pragma unroll
        for (int rr = 0; rr < 4; rr++)
            vpart[mi][rr] = 0.f;

    // A-frag: row R = wr + mi*16 + l15, logical chunk c = s*4+q, stored at c^(R&7)
#define A_FRAG(mi, s) (*(const bf16x8*)(&As[(wr + (mi)*16 + l15) * DD + ((((s)*4 + q) ^ r3) * 8)]))

    bf16x8 a[4][2];                    // ring-4 over s, 3-step lookahead
    #pragma unroll
    for (int g = 0; g < 3; g++) {
        a[g][0] = A_FRAG(0, g);
        a[g][1] = A_FRAG(1, g);
    }

    #pragma unroll 1
    for (int p = 0; p < 8; p++) {
        f32x4 acc[2][2];
        #pragma unroll
        for (int mi = 0; mi < 2; mi++)
            #pragma unroll
            for (int ni = 0; ni < 2; ni++)
                acc[mi][ni] = (f32x4){0.f, 0.f, 0.f, 0.f};

        #pragma unroll
        for (int s = 0; s < 16; s++) {
            const int ns = (s + 3) & 15;     // pass p+1 reuses same A data (wraps)
            a[(s + 3) & 3][0] = A_FRAG(0, ns);
            a[(s + 3) & 3][1] = A_FRAG(1, ns);
            // B stream, 3-step lookahead (stream padded: tail overrun harmless)
            b[(s + 3) & 3][0] = *(const bf16x8*)(bqp);
            b[(s + 3) & 3][1] = *(const bf16x8*)(bqp + 512);
            bqp += 1024;
            #pragma unroll
            for (int mi = 0; mi < 2; mi++)
                #pragma unroll
                for (int ni = 0; ni < 2; ni++)
                    acc[mi][ni] = __builtin_amdgcn_mfma_f32_16x16x32_bf16(
                        a[s & 3][mi], b[s & 3][ni], acc[mi][ni], 0, 0, 0);
        }

        // per-pass epilogue: tanh + v-dot into per-row partials
        // C/D layout (16x16): col = lane&15, row = q*4 + rr  [m89/m91 verified]
        float vv0 = v[wh * 256 + p * 32 + l15];
        float vv1 = v[wh * 256 + p * 32 + 16 + l15];
        #pragma unroll
        for (int mi = 0; mi < 2; mi++)
            #pragma unroll
            for (int rr = 0; rr < 4; rr++)
                vpart[mi][rr] += tanh_fast(acc[mi][0][rr]) * vv0
                               + tanh_fast(acc[mi][1][rr]) * vv1;
    }
#undef A_FRAG

    // cross-lane reduce over the 16 col-lanes -> per-col-half row partials
    #pragma unroll
    for (int mi = 0; mi < 2; mi++)
        #pragma unroll
        for (int rr = 0; rr < 4; rr++) {
            float sum = vpart[mi][rr];
            sum += __shfl_xor(sum, 1);
            sum += __shfl_xor(sum, 2);
            sum += __shfl_xor(sum, 4);
            sum += __shfl_xor(sum, 8);
            if (l15 == 0)
                sbuf[wh][wr + mi * 16 + q * 4 + rr] = sum;
        }
    __syncthreads();

    // wave 0: row scores -> block max m, e_r, Z
    if (tid < 64) {
        float s = sbuf[0][tid] + sbuf[1][tid];
        float m = s;
        #pragma unroll
        for (int off = 32; off; off >>= 1) m = fmaxf(m, __shfl_xor(m, off));
        float e = __expf(s - m);
        float z = e;
        #pragma unroll
        for (int off = 32; off; off >>= 1) z += __shfl_xor(z, off);
        ew[tid] = e;
        if (tid == 0) { mzsh[0] = m; mzsh[1] = z; }
    }
    __syncthreads();

    // weighted x-sum from LDS: thread = (rg = tid>>6 row group, cx = tid&63 chunk)
    // num[d] partial = sum_r e_r * xb[r][d]
    const int cx = tid & 63;
    const int rg = tid >> 6;
    float nacc[8];
    #pragma unroll
    for (int j = 0; j < 8; j++) nacc[j] = 0.f;
    #pragma unroll 4
    for (int i = 0; i < 16; i++) {
        int r = rg * 16 + i;
        uint4 u = *(const uint4*)(&As[r * DD + ((cx ^ (r & 7)) * 8)]);
        float e = ew[r];
        nacc[0] += e * __builtin_bit_cast(float, u.x << 16);
        nacc[1] += e * __builtin_bit_cast(float, u.x & 0xFFFF0000u);
        nacc[2] += e * __builtin_bit_cast(float, u.y << 16);
        nacc[3] += e * __builtin_bit_cast(float, u.y & 0xFFFF0000u);
        nacc[4] += e * __builtin_bit_cast(float, u.z << 16);
        nacc[5] += e * __builtin_bit_cast(float, u.z & 0xFFFF0000u);
        nacc[6] += e * __builtin_bit_cast(float, u.w << 16);
        nacc[7] += e * __builtin_bit_cast(float, u.w & 0xFFFF0000u);
    }
    *(float4*)(&psum[rg][cx * 8])     = *(float4*)(&nacc[0]);
    *(float4*)(&psum[rg][cx * 8 + 4]) = *(float4*)(&nacc[4]);
    __syncthreads();

    if (tid < 128) {
        int c = tid * 4;
        f32x4 f = *(const f32x4*)(&psum[0][c]);
        f += *(const f32x4*)(&psum[1][c]);
        f += *(const f32x4*)(&psum[2][c]);
        f += *(const f32x4*)(&psum[3][c]);
        __builtin_nontemporal_store(f, (f32x4*)(num_ws + (size_t)blockIdx.x * DD + c));
    }
    if (tid == 0) {
        mz_ws[2 * blockIdx.x]     = mzsh[0];
        mz_ws[2 * blockIdx.x + 1] = mzsh[1];
    }
}

// ---------------- Combine: merge 64 chunk-partials per batch -> out[b][512] ----------------
__global__ void combine_kernel(const float* __restrict__ num_ws,
                               const float* __restrict__ mz_ws,
                               float* __restrict__ out) {
    __shared__ float fs[64];
    __shared__ float sinv_sh;
    const int b   = blockIdx.x;
    const int tid = threadIdx.x;

    if (tid < 64) {
        float m = mz_ws[(b * 64 + tid) * 2];
        float z = mz_ws[(b * 64 + tid) * 2 + 1];
        float M = m;
        #pragma unroll
        for (int off = 32; off; off >>= 1) M = fmaxf(M, __shfl_xor(M, off));
        float f  = __expf(m - M);
        float fz = f * z;
        #pragma unroll
        for (int off = 32; off; off >>= 1) fz += __shfl_xor(fz, off);
        fs[tid] = f;
        if (tid == 0) sinv_sh = 1.0f / fz;
    }
    __syncthreads();

    float a0 = 0.f, a1 = 0.f;
    #pragma unroll 4
    for (int c = 0; c < 64; c++) {
        float f = fs[c];
        const float* np = num_ws + (size_t)(b * 64 + c) * DD;
        a0 += f * np[tid];
        a1 += f * np[tid + 256];
    }
    const float sinv = sinv_sh;
    out[b * DD + tid]       = a0 * sinv;
    out[b * DD + tid + 256] = a1 * sinv;
}

extern "C" void kernel_launch(void* const* d_in, const int* in_sizes, int n_in,
                              void* d_out, int out_size, void* d_ws, size_t ws_size,
                              hipStream_t stream) {
    (void)in_sizes; (void)n_in; (void)out_size; (void)ws_size;
    const float* x = (const float*)d_in[0];
    const float* W = (const float*)d_in[1];
    const float* v = (const float*)d_in[2];
    float* out = (float*)d_out;

    // ws: Wb 512 KB + 16 KB stream-overrun pad | num 1024x512 fp32 (2 MB) | mz 1024x2 fp32
    unsigned short* Wb = (unsigned short*)d_ws;
    float* num_ws      = (float*)((char*)d_ws + 512 * 1024 + 16 * 1024);
    float* mz_ws       = (float*)((char*)d_ws + 512 * 1024 + 16 * 1024 + 2 * 1024 * 1024);

    wb_kernel<<<128, 256, 0, stream>>>(W, Wb);

    scorepool_kernel<<<MM / 64, 256, 0, stream>>>(x, Wb, v, num_ws, mz_ws);

    combine_kernel<<<BB, 256, 0, stream>>>(num_ws, mz_ws, out);
}